// Round 1
// 885.967 us; speedup vs baseline: 1.1583x; 1.1583x over previous
//
#include <hip/hip_runtime.h>
#include <hip/hip_bf16.h>
#include <stdint.h>

typedef __bf16 bf16;
typedef __bf16 v8bf __attribute__((ext_vector_type(8)));
typedef float  v4f  __attribute__((ext_vector_type(4)));
typedef float  f32x16 __attribute__((ext_vector_type(16)));

#define MFMA_BF16(a,b,c) __builtin_amdgcn_mfma_f32_16x16x32_bf16((a),(b),(c),0,0,0)
#define MFMA32(a,b,c)    __builtin_amdgcn_mfma_f32_32x32x16_bf16((a),(b),(c),0,0,0)

__device__ __forceinline__ void glds16(const bf16* g, bf16* l) {
  __builtin_amdgcn_global_load_lds(
      (const __attribute__((address_space(1))) void*)g,
      (__attribute__((address_space(3))) void*)l, 16, 0, 0);
}

__device__ __forceinline__ float wred_sum(float v) {
#pragma unroll
  for (int o = 32; o; o >>= 1) v += __shfl_xor(v, o);
  return v;
}
__device__ __forceinline__ float wred_max(float v) {
#pragma unroll
  for (int o = 32; o; o >>= 1) v = fmaxf(v, __shfl_xor(v, o));
  return v;
}

__device__ __forceinline__ unsigned int packbf(float a, float b) {
  union { bf16 h[2]; unsigned int u; } x;
  x.h[0] = (bf16)a; x.h[1] = (bf16)b;
  return x.u;
}

// ---------------- dtype sniffer (inputs turned out fp32; keep robust) ----------------
__global__ void k_sniff(const unsigned short* __restrict__ x, int* __restrict__ flag) {
  int cnt = 0;
  for (int i = threadIdx.x; i < 2048; i += 64) {
    const unsigned short u = x[i];
    const int e = (u >> 7) & 0xFF;
    if (u == 0 || (e >= 100 && e <= 140)) cnt++;
  }
#pragma unroll
  for (int o = 32; o; o >>= 1) cnt += __shfl_xor(cnt, o);
  if (threadIdx.x == 0) flag[0] = (cnt >= 1844) ? 0 : 1;  // 0 = bf16, 1 = f32
}

// ---------------- small utility kernels ----------------

__global__ void k_zero(float* p, int n) {
  int i = threadIdx.x;
  if (i < n) p[i] = 0.0f;
}

__global__ __launch_bounds__(256) void k_abssum(const void* __restrict__ w, int n,
                                                const int* __restrict__ flag,
                                                float* __restrict__ out) {
  const int tid = threadIdx.x;
  const int f32 = flag[0];
  __shared__ float sred[4];
  float s = 0.0f;
  if (f32) {
    const float4* p = (const float4*)w;
    for (int i = (blockIdx.x * 256 + tid) * 2; i * 4 < n; i += gridDim.x * 512) {
      float4 a = p[i], b = p[i + 1];
      s += fabsf(a.x) + fabsf(a.y) + fabsf(a.z) + fabsf(a.w) +
           fabsf(b.x) + fabsf(b.y) + fabsf(b.z) + fabsf(b.w);
    }
  } else {
    const bf16* p = (const bf16*)w;
    for (int i = (blockIdx.x * 256 + tid) * 8; i < n; i += gridDim.x * 2048) {
      v8bf v = *(const v8bf*)(p + i);
#pragma unroll
      for (int j = 0; j < 8; j++) s += fabsf((float)v[j]);
    }
  }
  s = wred_sum(s);
  if ((tid & 63) == 0) sred[tid >> 6] = s;
  __syncthreads();
  if (tid == 0) atomicAdd(out, sred[0] + sred[1] + sred[2] + sred[3]);
}

__global__ __launch_bounds__(256) void k_wquant(const void* __restrict__ w, bf16* __restrict__ o,
                                                const float* __restrict__ sum, float invn,
                                                const int* __restrict__ flag) {
  const int gid = blockIdx.x * 256 + threadIdx.x;
  const int i = gid * 8;
  const float ws = 1.0f / fmaxf(sum[0] * invn, 1e-5f);
  const int f32 = flag[0];
  float v[8];
  if (f32) {
    float4 a = ((const float4*)w)[gid * 2];
    float4 b = ((const float4*)w)[gid * 2 + 1];
    v[0] = a.x; v[1] = a.y; v[2] = a.z; v[3] = a.w;
    v[4] = b.x; v[5] = b.y; v[6] = b.z; v[7] = b.w;
  } else {
    v8bf t = *(const v8bf*)((const bf16*)w + i);
#pragma unroll
    for (int j = 0; j < 8; j++) v[j] = (float)t[j];
  }
  v8bf r;
#pragma unroll
  for (int j = 0; j < 8; j++) {
    float t = rintf(v[j] * ws);
    r[j] = (bf16)fminf(fmaxf(t, -1.0f), 1.0f);
  }
  *(v8bf*)(o + i) = r;
}

// LayerNorm + per-row absmax quantize (integer-valued bf16 out).
template <bool XINT>
__global__ __launch_bounds__(256) void k_lnq(const void* __restrict__ x, const void* __restrict__ g,
                                             const void* __restrict__ b, bf16* __restrict__ q,
                                             float* __restrict__ sc, const int* __restrict__ flag) {
  const int row = blockIdx.x, tid = threadIdx.x;
  const int f32 = flag[0];
  __shared__ float sred[4];
  float v[8];
#pragma unroll
  for (int i = 0; i < 8; i++) {
    const size_t idx = (size_t)row * 2048 + tid + 256 * i;
    if (XINT)      v[i] = ((const float*)x)[idx];
    else if (f32)  v[i] = ((const float*)x)[idx];
    else           v[i] = (float)((const bf16*)x)[idx];
  }
  float s = 0.0f;
#pragma unroll
  for (int i = 0; i < 8; i++) s += v[i];
  s = wred_sum(s);
  if ((tid & 63) == 0) sred[tid >> 6] = s;
  __syncthreads();
  const float mean = (sred[0] + sred[1] + sred[2] + sred[3]) * (1.0f / 2048.0f);
  __syncthreads();
  float vs = 0.0f;
#pragma unroll
  for (int i = 0; i < 8; i++) { float d = v[i] - mean; vs += d * d; }
  vs = wred_sum(vs);
  if ((tid & 63) == 0) sred[tid >> 6] = vs;
  __syncthreads();
  const float rstd = rsqrtf((sred[0] + sred[1] + sred[2] + sred[3]) * (1.0f / 2048.0f) + 1e-6f);
  __syncthreads();
  float hq[8];
  float am = 0.0f;
#pragma unroll
  for (int i = 0; i < 8; i++) {
    const int c = tid + 256 * i;
    const float gv = f32 ? ((const float*)g)[c] : (float)((const bf16*)g)[c];
    const float bv = f32 ? ((const float*)b)[c] : (float)((const bf16*)b)[c];
    hq[i] = (v[i] - mean) * rstd * gv + bv;
    am = fmaxf(am, fabsf(hq[i]));
  }
  am = wred_max(am);
  if ((tid & 63) == 0) sred[tid >> 6] = am;
  __syncthreads();
  am = fmaxf(fmaxf(sred[0], sred[1]), fmaxf(sred[2], sred[3]));
  const float cl = fmaxf(am, 1e-5f);
  const float s127 = 127.0f / cl;
#pragma unroll
  for (int i = 0; i < 8; i++) {
    float r = rintf(hq[i] * s127);
    r = fminf(fmaxf(r, -128.0f), 127.0f);
    q[(size_t)row * 2048 + tid + 256 * i] = (bf16)r;
  }
  if (tid == 0) sc[row] = cl * (1.0f / 127.0f);
}

// plain per-row absmax quantize; safe in-place
template <int IT>
__global__ __launch_bounds__(256) void k_rowq(const bf16* __restrict__ in, bf16* __restrict__ q,
                                              float* __restrict__ sc) {
  const int row = blockIdx.x, tid = threadIdx.x;
  const int C = IT * 256;
  __shared__ float sred[4];
  const bf16* xr = in + (size_t)row * C;
  float v[IT];
  float am = 0.0f;
#pragma unroll
  for (int i = 0; i < IT; i++) {
    v[i] = (float)xr[tid + 256 * i];
    am = fmaxf(am, fabsf(v[i]));
  }
  am = wred_max(am);
  if ((tid & 63) == 0) sred[tid >> 6] = am;
  __syncthreads();
  am = fmaxf(fmaxf(sred[0], sred[1]), fmaxf(sred[2], sred[3]));
  const float cl = fmaxf(am, 1e-5f);
  const float s127 = 127.0f / cl;
#pragma unroll
  for (int i = 0; i < IT; i++) {
    float r = rintf(v[i] * s127);
    r = fminf(fmaxf(r, -128.0f), 127.0f);
    q[(size_t)row * C + tid + 256 * i] = (bf16)r;
  }
  if (tid == 0) sc[row] = cl * (1.0f / 127.0f);
}

// transpose V (2048 x 512) -> Vt (512 x 2048)
__global__ __launch_bounds__(256) void k_vt(const bf16* __restrict__ V, bf16* __restrict__ Vt) {
  const int gid = blockIdx.x * 256 + threadIdx.x;
  const int d = gid >> 8;          // 0..511
  const int t0 = (gid & 255) * 8;  // 0..2040
  v8bf v;
#pragma unroll
  for (int i = 0; i < 8; i++) v[i] = V[(size_t)(t0 + i) * 512 + d];
  *(v8bf*)(Vt + (size_t)d * 2048 + t0) = v;
}

// ---------------- GEMM (m97 structure: global_load_lds width-16 staging) ----------------
// C[t,n] = sA[t]*cw * sum_k A[t,k]*B[n,k];  A,B internal bf16 (integer-valued).
// EPI 0: out bf16 = val                        (QKV projections)
// EPI 1: out f32  = resid(ext, per flag) + val (wo projection -> x1)
// EPI 2: out bf16 = relu(val)^2                (w1 -> F)
// EPI 3: out(ext, per flag) = f32 resid + val (w2 -> final output)
template <int EPI>
__global__ __launch_bounds__(256) void k_gemm(const bf16* __restrict__ A, const bf16* __restrict__ B,
                                              const float* __restrict__ sA,
                                              const float* __restrict__ wsum, float winv,
                                              const void* __restrict__ resid, void* __restrict__ out,
                                              int M, int N, int K, const int* __restrict__ flag) {
  __shared__ __align__(16) bf16 As[128 * 32];
  __shared__ __align__(16) bf16 Bs[128 * 32];
  const int tid = threadIdx.x;
  const int lane = tid & 63;
  const int ml = lane & 15;
  const int q4 = lane >> 4;
  const int wid = tid >> 6;
  const int wM = wid >> 1;
  const int wN = wid & 1;
  const int m0 = blockIdx.y * 128;
  const int n0 = blockIdx.x * 128;

  const int r0 = tid >> 2;          // 0..63
  const int c0 = (tid & 3) * 8;     // 0,8,16,24
  const bf16* Ag0 = A + (size_t)(m0 + r0) * K + c0;
  const bf16* Ag1 = Ag0 + (size_t)64 * K;
  const bf16* Bg0 = B + (size_t)(n0 + r0) * K + c0;
  const bf16* Bg1 = Bg0 + (size_t)64 * K;
  // lane l of wave w writes LDS at base + l*16B == &As[(w*64+l)*8] == As[tid*8]
  bf16* as0 = &As[wid * 512];
  bf16* as1 = &As[2048 + wid * 512];
  bf16* bs0 = &Bs[wid * 512];
  bf16* bs1 = &Bs[2048 + wid * 512];

  v4f acc[4][4] = {};

  for (int k0 = 0; k0 < K; k0 += 32) {
    __syncthreads();  // prior iteration's readers done before overwrite
    glds16(Ag0 + k0, as0);
    glds16(Ag1 + k0, as1);
    glds16(Bg0 + k0, bs0);
    glds16(Bg1 + k0, bs1);
    __syncthreads();  // staging complete (barrier drains vmcnt)
    v8bf af[4], bfr[4];
#pragma unroll
    for (int i = 0; i < 4; i++) af[i] = *(const v8bf*)&As[(wM * 64 + i * 16 + ml) * 32 + q4 * 8];
#pragma unroll
    for (int j = 0; j < 4; j++) bfr[j] = *(const v8bf*)&Bs[(wN * 64 + j * 16 + ml) * 32 + q4 * 8];
#pragma unroll
    for (int i = 0; i < 4; i++)
#pragma unroll
      for (int j = 0; j < 4; j++) acc[i][j] = MFMA_BF16(af[i], bfr[j], acc[i][j]);
  }

  const float cw = fmaxf(wsum[0] * winv, 1e-5f);
  const int f32 = flag[0];
#pragma unroll
  for (int i = 0; i < 4; i++) {
#pragma unroll
    for (int r = 0; r < 4; r++) {
      const int row = m0 + wM * 64 + i * 16 + q4 * 4 + r;
      const float sa = sA[row] * cw;
#pragma unroll
      for (int j = 0; j < 4; j++) {
        const int col = n0 + wN * 64 + j * 16 + ml;
        const float val = acc[i][j][r] * sa;
        const size_t idx = (size_t)row * N + col;
        if (EPI == 0) {
          ((bf16*)out)[idx] = (bf16)val;
        } else if (EPI == 1) {
          const float rv = f32 ? ((const float*)resid)[idx] : (float)((const bf16*)resid)[idx];
          ((float*)out)[idx] = rv + val;
        } else if (EPI == 2) {
          float u = fmaxf(val, 0.0f);
          ((bf16*)out)[idx] = (bf16)(u * u);
        } else {
          const float ov = ((const float*)resid)[idx] + val;
          if (f32) ((float*)out)[idx] = ov;
          else     ((bf16*)out)[idx] = (bf16)ov;
        }
      }
    }
  }
}

// ---------------- MFMA flash attention (causal, GQA 32q/8kv heads, D=64) ----------------
// Swapped-operand 32x32 structure (m214-style): one wave per 32 queries.
// S^T = mfma_32x32x16(K-frag, Q-frag): lane owns query q = lane&31;
// k spread over 16 regs + partner lane (lane^32): k = (r&3) + 8*(r>>2) + 4*hi.
// Softmax fully in-register: row-reduce = 15 ops + 1 shfl_xor(32).
// P^T -> PV B-frags via packed bf16 pairs + v_permlane32_swap (no LDS at all).
// O^T accumulated as two 32x32 tiles (d-blocks); K/V frags straight from L2.
// Block = 1 wave (64 thr); grid (64, 32); t-swizzle spreads the causal triangle
// across CUs: t = (bx + 8*(h>>2)) & 63  (bijective per head; each CU's resident
// set spans light..heavy tiles).
__global__ __launch_bounds__(64) void k_attn(const bf16* __restrict__ Q, const bf16* __restrict__ Kb,
                                             const bf16* __restrict__ Vt, bf16* __restrict__ O) {
  const int h = blockIdx.y;
  const int kvh = h >> 2;
  const int t = (blockIdx.x + ((h >> 2) << 3)) & 63;  // balanced q-tile swizzle
  const int qw0 = t * 32;
  const int lane = threadIdx.x;
  const int ql = lane & 31;
  const int hi = lane >> 5;

  // Q fragments: B-operand of S^T-MFMA; lane holds Q[qw0+ql][d0 + hi*8 + e]
  v8bf qf[4];
  {
    const bf16* qp = Q + (size_t)(qw0 + ql) * 2048 + h * 64 + hi * 8;
#pragma unroll
    for (int c = 0; c < 4; c++) qf[c] = *(const v8bf*)(qp + c * 16);
  }

  float m = -1e30f, l = 0.0f;
  f32x16 acc0 = {}, acc1 = {};  // O^T d-blocks [0,32) and [32,64)

  const bf16* kbase = Kb + kvh * 64 + hi * 8;
  const bf16* vbase = Vt + (size_t)(kvh * 64 + ql) * 2048 + hi * 8;

  for (int kb = 0; kb <= qw0; kb += 32) {
    // S^T = K . Q^T  (A = K rows, contraction over d in 4 chunks of 16)
    f32x16 s = {};
    {
      const bf16* kp = kbase + (size_t)(kb + ql) * 512;
#pragma unroll
      for (int c = 0; c < 4; c++) {
        const v8bf kf = *(const v8bf*)(kp + c * 16);
        s = MFMA32(kf, qf[c], s);
      }
    }
    const bool diag = (kb == qw0);
    float p[16];
    float rm = -1e30f;
#pragma unroll
    for (int r = 0; r < 16; r++) {
      float v = s[r] * 0.125f;
      const int koff = (r & 3) + ((r >> 2) << 3) + (hi << 2);
      if (diag && koff > ql) v = -1e30f;  // causal mask on diagonal tile
      p[r] = v;
      rm = fmaxf(rm, v);
    }
    rm = fmaxf(rm, __shfl_xor(rm, 32));  // combine hi/lo k-halves
    const float mn = fmaxf(m, rm);
    const float alpha = __expf(m - mn);
    m = mn;
    float rs = 0.0f;
#pragma unroll
    for (int r = 0; r < 16; r++) {
      p[r] = __expf(p[r] - mn);
      rs += p[r];
    }
    rs += __shfl_xor(rs, 32);
    l = l * alpha + rs;
#pragma unroll
    for (int r = 0; r < 16; r++) { acc0[r] *= alpha; acc1[r] *= alpha; }

    // P^T -> PV B-fragments. Lane holds k = (r&3)+8*(r>>2)+4*hi for its q.
    // B-frag needs k = 8*hi + j (j=0..7) per 16-k step. Pack bf16 pairs, then
    // permlane32_swap: a.hi-lanes <- b.lo-lanes, b.lo-lanes <- a.hi-lanes.
    unsigned int w0 = packbf(p[0], p[1]),   w2 = packbf(p[4], p[5]);
    unsigned int w1 = packbf(p[2], p[3]),   w3 = packbf(p[6], p[7]);
    unsigned int x0 = packbf(p[8], p[9]),   x2 = packbf(p[12], p[13]);
    unsigned int x1 = packbf(p[10], p[11]), x3 = packbf(p[14], p[15]);
    asm("v_permlane32_swap_b32 %0, %1" : "+v"(w0), "+v"(w2));
    asm("v_permlane32_swap_b32 %0, %1" : "+v"(w1), "+v"(w3));
    asm("v_permlane32_swap_b32 %0, %1" : "+v"(x0), "+v"(x2));
    asm("v_permlane32_swap_b32 %0, %1" : "+v"(x1), "+v"(x3));
    union BU { unsigned int u[4]; v8bf v; } B0, B1;
    B0.u[0] = w0; B0.u[1] = w1; B0.u[2] = w2; B0.u[3] = w3;  // k = 0..15
    B1.u[0] = x0; B1.u[1] = x1; B1.u[2] = x2; B1.u[3] = x3;  // k = 16..31

    // O^T += V^T . P^T   (A = V^T rows = d, contraction over k in 2 chunks)
    const bf16* vp = vbase + kb;
    const v8bf v00 = *(const v8bf*)(vp);
    const v8bf v01 = *(const v8bf*)(vp + 16);
    const v8bf v10 = *(const v8bf*)(vp + (size_t)32 * 2048);
    const v8bf v11 = *(const v8bf*)(vp + (size_t)32 * 2048 + 16);
    acc0 = MFMA32(v00, B0.v, acc0);
    acc0 = MFMA32(v01, B1.v, acc0);
    acc1 = MFMA32(v10, B0.v, acc1);
    acc1 = MFMA32(v11, B1.v, acc1);
  }

  // epilogue: lane holds O^T[d][q=ql], d = dblk*32 + (r&3)+8*(r>>2)+4*hi.
  // r even pairs (r, r+1) -> adjacent d -> packed dword stores.
  const float inv = 1.0f / l;
  unsigned int* op = (unsigned int*)(O + (size_t)(qw0 + ql) * 2048 + h * 64);
#pragma unroll
  for (int r = 0; r < 16; r += 2) {
    const int d = (r & 3) + ((r >> 2) << 3) + (hi << 2);
    op[d >> 1] = packbf(acc0[r] * inv, acc0[r + 1] * inv);
    op[(d >> 1) + 16] = packbf(acc1[r] * inv, acc1[r + 1] * inv);
  }
}

// ---------------- launcher ----------------
// Workspace (96 MB + 64 KB):
//   scalars: wsum[8]@0, s1@8K, so@16K, s2@24K, sf@32K, flag@40K
//   R0 [ 0,32)MB: w1z ............. then w2z (quant AFTER gemm<2>)
//   R1 [32,64)MB: wqz+0 wkz+8 wvz+10 woz+12, then Fb/fq (in-place rowq)
//   R2 [64,80)MB: Qb+0 Kbuf+8 Vb+10 Vt+12, then x1 (fp32, after attention)
//   R3 [80,88)MB: xq1 -> oq -> xq2
//   R4 [88,96)MB: Ob
extern "C" void kernel_launch(void* const* d_in, const int* in_sizes, int n_in, void* d_out,
                              int out_size, void* d_ws, size_t ws_size, hipStream_t stream) {
  const void* x = d_in[0];
  const void* g1 = d_in[1];
  const void* b1 = d_in[2];
  const void* g2 = d_in[3];
  const void* b2 = d_in[4];
  const void* wq = d_in[5];
  const void* wk = d_in[6];
  const void* wv = d_in[7];
  const void* wo = d_in[8];
  const void* w1 = d_in[9];
  const void* w2 = d_in[10];

  char* ws = (char*)d_ws;
  const size_t MB = 1ull << 20;
  float* wsum = (float*)ws;
  float* s1 = (float*)(ws + 8192);
  float* so = (float*)(ws + 16384);
  float* s2 = (float*)(ws + 24576);
  float* sf = (float*)(ws + 32768);
  int* flag = (int*)(ws + 40960);
  char* big = ws + 65536;

  bf16* w1z = (bf16*)(big);
  bf16* w2z = (bf16*)(big);
  bf16* wqz = (bf16*)(big + 32 * MB);
  bf16* wkz = (bf16*)(big + 40 * MB);
  bf16* wvz = (bf16*)(big + 42 * MB);
  bf16* woz = (bf16*)(big + 44 * MB);
  bf16* Fb  = (bf16*)(big + 32 * MB);
  bf16* fq  = Fb;
  bf16* Qb   = (bf16*)(big + 64 * MB);
  bf16* Kbuf = (bf16*)(big + 72 * MB);
  bf16* Vb   = (bf16*)(big + 74 * MB);
  bf16* Vt   = (bf16*)(big + 76 * MB);
  float* x1  = (float*)(big + 64 * MB);
  bf16* xq1 = (bf16*)(big + 80 * MB);
  bf16* oq  = xq1;
  bf16* xq2 = xq1;
  bf16* Ob  = (bf16*)(big + 88 * MB);

  const float invD2 = 1.0f / 4194304.0f;
  const float invKV = 1.0f / 1048576.0f;
  const float invF = 1.0f / 16777216.0f;

  k_sniff<<<1, 64, 0, stream>>>((const unsigned short*)x, flag);
  k_zero<<<1, 64, 0, stream>>>(wsum, 8);
  k_abssum<<<512, 256, 0, stream>>>(wq, 2048 * 2048, flag, wsum + 0);
  k_abssum<<<512, 256, 0, stream>>>(wk, 512 * 2048, flag, wsum + 1);
  k_abssum<<<512, 256, 0, stream>>>(wv, 512 * 2048, flag, wsum + 2);
  k_abssum<<<512, 256, 0, stream>>>(wo, 2048 * 2048, flag, wsum + 3);
  k_abssum<<<512, 256, 0, stream>>>(w1, 8192 * 2048, flag, wsum + 4);
  k_abssum<<<512, 256, 0, stream>>>(w2, 2048 * 8192, flag, wsum + 5);
  k_wquant<<<2048, 256, 0, stream>>>(wq, wqz, wsum + 0, invD2, flag);
  k_wquant<<<512, 256, 0, stream>>>(wk, wkz, wsum + 1, invKV, flag);
  k_wquant<<<512, 256, 0, stream>>>(wv, wvz, wsum + 2, invKV, flag);
  k_wquant<<<2048, 256, 0, stream>>>(wo, woz, wsum + 3, invD2, flag);
  k_wquant<<<8192, 256, 0, stream>>>(w1, w1z, wsum + 4, invF, flag);

  // attention sublayer
  k_lnq<false><<<2048, 256, 0, stream>>>(x, g1, b1, xq1, s1, flag);
  k_gemm<0><<<dim3(16, 16), 256, 0, stream>>>(xq1, wqz, s1, wsum + 0, invD2, nullptr, Qb, 2048, 2048, 2048, flag);
  k_gemm<0><<<dim3(4, 16), 256, 0, stream>>>(xq1, wkz, s1, wsum + 1, invKV, nullptr, Kbuf, 2048, 512, 2048, flag);
  k_gemm<0><<<dim3(4, 16), 256, 0, stream>>>(xq1, wvz, s1, wsum + 2, invKV, nullptr, Vb, 2048, 512, 2048, flag);
  k_vt<<<512, 256, 0, stream>>>(Vb, Vt);
  k_attn<<<dim3(64, 32), 64, 0, stream>>>(Qb, Kbuf, Vt, Ob);
  k_rowq<8><<<2048, 256, 0, stream>>>(Ob, oq, so);
  k_gemm<1><<<dim3(16, 16), 256, 0, stream>>>(oq, woz, so, wsum + 3, invD2, x, x1, 2048, 2048, 2048, flag);

  // FFN sublayer
  k_lnq<true><<<2048, 256, 0, stream>>>(x1, g2, b2, xq2, s2, flag);
  k_gemm<2><<<dim3(64, 16), 256, 0, stream>>>(xq2, w1z, s2, wsum + 4, invF, nullptr, Fb, 2048, 8192, 2048, flag);
  k_wquant<<<8192, 256, 0, stream>>>(w2, w2z, wsum + 5, invF, flag);
  k_rowq<32><<<2048, 256, 0, stream>>>(Fb, fq, sf);
  k_gemm<3><<<dim3(16, 16), 256, 0, stream>>>(fq, w2z, sf, wsum + 5, invF, x1, d_out, 2048, 2048, 8192, flag);
}

// Round 2
// 847.427 us; speedup vs baseline: 1.2110x; 1.0455x over previous
//
#include <hip/hip_runtime.h>
#include <hip/hip_bf16.h>
#include <stdint.h>

typedef __bf16 bf16;
typedef __bf16 v8bf __attribute__((ext_vector_type(8)));
typedef __bf16 v4bf __attribute__((ext_vector_type(4)));
typedef float  v4f  __attribute__((ext_vector_type(4)));
typedef float  f32x16 __attribute__((ext_vector_type(16)));

#define MFMA_BF16(a,b,c) __builtin_amdgcn_mfma_f32_16x16x32_bf16((a),(b),(c),0,0,0)
#define MFMA32(a,b,c)    __builtin_amdgcn_mfma_f32_32x32x16_bf16((a),(b),(c),0,0,0)

__device__ __forceinline__ void glds16(const bf16* g, bf16* l) {
  __builtin_amdgcn_global_load_lds(
      (const __attribute__((address_space(1))) void*)g,
      (__attribute__((address_space(3))) void*)l, 16, 0, 0);
}

__device__ __forceinline__ float wred_sum(float v) {
#pragma unroll
  for (int o = 32; o; o >>= 1) v += __shfl_xor(v, o);
  return v;
}
__device__ __forceinline__ float wred_max(float v) {
#pragma unroll
  for (int o = 32; o; o >>= 1) v = fmaxf(v, __shfl_xor(v, o));
  return v;
}

__device__ __forceinline__ unsigned int packbf(float a, float b) {
  union { bf16 h[2]; unsigned int u; } x;
  x.h[0] = (bf16)a; x.h[1] = (bf16)b;
  return x.u;
}

// ---------------- dtype sniffer (inputs turned out fp32; keep robust) ----------------
__global__ void k_sniff(const unsigned short* __restrict__ x, int* __restrict__ flag) {
  int cnt = 0;
  for (int i = threadIdx.x; i < 2048; i += 64) {
    const unsigned short u = x[i];
    const int e = (u >> 7) & 0xFF;
    if (u == 0 || (e >= 100 && e <= 140)) cnt++;
  }
#pragma unroll
  for (int o = 32; o; o >>= 1) cnt += __shfl_xor(cnt, o);
  if (threadIdx.x == 0) flag[0] = (cnt >= 1844) ? 0 : 1;  // 0 = bf16, 1 = f32
}

// ---------------- small utility kernels ----------------

__global__ void k_zero(float* p, int n) {
  int i = threadIdx.x;
  if (i < n) p[i] = 0.0f;
}

// zero a float4-aligned buffer; grid = bytes/16/256
__global__ __launch_bounds__(256) void k_zerof(float4* __restrict__ p) {
  p[(size_t)blockIdx.x * 256 + threadIdx.x] = make_float4(0.f, 0.f, 0.f, 0.f);
}

__global__ __launch_bounds__(256) void k_abssum(const void* __restrict__ w, int n,
                                                const int* __restrict__ flag,
                                                float* __restrict__ out) {
  const int tid = threadIdx.x;
  const int f32 = flag[0];
  __shared__ float sred[4];
  float s = 0.0f;
  if (f32) {
    const float4* p = (const float4*)w;
    for (int i = (blockIdx.x * 256 + tid) * 2; i * 4 < n; i += gridDim.x * 512) {
      float4 a = p[i], b = p[i + 1];
      s += fabsf(a.x) + fabsf(a.y) + fabsf(a.z) + fabsf(a.w) +
           fabsf(b.x) + fabsf(b.y) + fabsf(b.z) + fabsf(b.w);
    }
  } else {
    const bf16* p = (const bf16*)w;
    for (int i = (blockIdx.x * 256 + tid) * 8; i < n; i += gridDim.x * 2048) {
      v8bf v = *(const v8bf*)(p + i);
#pragma unroll
      for (int j = 0; j < 8; j++) s += fabsf((float)v[j]);
    }
  }
  s = wred_sum(s);
  if ((tid & 63) == 0) sred[tid >> 6] = s;
  __syncthreads();
  if (tid == 0) atomicAdd(out, sred[0] + sred[1] + sred[2] + sred[3]);
}

__global__ __launch_bounds__(256) void k_wquant(const void* __restrict__ w, bf16* __restrict__ o,
                                                const float* __restrict__ sum, float invn,
                                                const int* __restrict__ flag) {
  const int gid = blockIdx.x * 256 + threadIdx.x;
  const int i = gid * 8;
  const float ws = 1.0f / fmaxf(sum[0] * invn, 1e-5f);
  const int f32 = flag[0];
  float v[8];
  if (f32) {
    float4 a = ((const float4*)w)[gid * 2];
    float4 b = ((const float4*)w)[gid * 2 + 1];
    v[0] = a.x; v[1] = a.y; v[2] = a.z; v[3] = a.w;
    v[4] = b.x; v[5] = b.y; v[6] = b.z; v[7] = b.w;
  } else {
    v8bf t = *(const v8bf*)((const bf16*)w + i);
#pragma unroll
    for (int j = 0; j < 8; j++) v[j] = (float)t[j];
  }
  v8bf r;
#pragma unroll
  for (int j = 0; j < 8; j++) {
    float t = rintf(v[j] * ws);
    r[j] = (bf16)fminf(fmaxf(t, -1.0f), 1.0f);
  }
  *(v8bf*)(o + i) = r;
}

// LayerNorm + per-row absmax quantize (integer-valued bf16 out).
template <bool XINT>
__global__ __launch_bounds__(256) void k_lnq(const void* __restrict__ x, const void* __restrict__ g,
                                             const void* __restrict__ b, bf16* __restrict__ q,
                                             float* __restrict__ sc, const int* __restrict__ flag) {
  const int row = blockIdx.x, tid = threadIdx.x;
  const int f32 = flag[0];
  __shared__ float sred[4];
  float v[8];
#pragma unroll
  for (int i = 0; i < 8; i++) {
    const size_t idx = (size_t)row * 2048 + tid + 256 * i;
    if (XINT)      v[i] = ((const float*)x)[idx];
    else if (f32)  v[i] = ((const float*)x)[idx];
    else           v[i] = (float)((const bf16*)x)[idx];
  }
  float s = 0.0f;
#pragma unroll
  for (int i = 0; i < 8; i++) s += v[i];
  s = wred_sum(s);
  if ((tid & 63) == 0) sred[tid >> 6] = s;
  __syncthreads();
  const float mean = (sred[0] + sred[1] + sred[2] + sred[3]) * (1.0f / 2048.0f);
  __syncthreads();
  float vs = 0.0f;
#pragma unroll
  for (int i = 0; i < 8; i++) { float d = v[i] - mean; vs += d * d; }
  vs = wred_sum(vs);
  if ((tid & 63) == 0) sred[tid >> 6] = vs;
  __syncthreads();
  const float rstd = rsqrtf((sred[0] + sred[1] + sred[2] + sred[3]) * (1.0f / 2048.0f) + 1e-6f);
  __syncthreads();
  float hq[8];
  float am = 0.0f;
#pragma unroll
  for (int i = 0; i < 8; i++) {
    const int c = tid + 256 * i;
    const float gv = f32 ? ((const float*)g)[c] : (float)((const bf16*)g)[c];
    const float bv = f32 ? ((const float*)b)[c] : (float)((const bf16*)b)[c];
    hq[i] = (v[i] - mean) * rstd * gv + bv;
    am = fmaxf(am, fabsf(hq[i]));
  }
  am = wred_max(am);
  if ((tid & 63) == 0) sred[tid >> 6] = am;
  __syncthreads();
  am = fmaxf(fmaxf(sred[0], sred[1]), fmaxf(sred[2], sred[3]));
  const float cl = fmaxf(am, 1e-5f);
  const float s127 = 127.0f / cl;
#pragma unroll
  for (int i = 0; i < 8; i++) {
    float r = rintf(hq[i] * s127);
    r = fminf(fmaxf(r, -128.0f), 127.0f);
    q[(size_t)row * 2048 + tid + 256 * i] = (bf16)r;
  }
  if (tid == 0) sc[row] = cl * (1.0f / 127.0f);
}

// plain per-row absmax quantize; safe in-place
template <int IT>
__global__ __launch_bounds__(256) void k_rowq(const bf16* __restrict__ in, bf16* __restrict__ q,
                                              float* __restrict__ sc) {
  const int row = blockIdx.x, tid = threadIdx.x;
  const int C = IT * 256;
  __shared__ float sred[4];
  const bf16* xr = in + (size_t)row * C;
  float v[IT];
  float am = 0.0f;
#pragma unroll
  for (int i = 0; i < IT; i++) {
    v[i] = (float)xr[tid + 256 * i];
    am = fmaxf(am, fabsf(v[i]));
  }
  am = wred_max(am);
  if ((tid & 63) == 0) sred[tid >> 6] = am;
  __syncthreads();
  am = fmaxf(fmaxf(sred[0], sred[1]), fmaxf(sred[2], sred[3]));
  const float cl = fmaxf(am, 1e-5f);
  const float s127 = 127.0f / cl;
#pragma unroll
  for (int i = 0; i < IT; i++) {
    float r = rintf(v[i] * s127);
    r = fminf(fmaxf(r, -128.0f), 127.0f);
    q[(size_t)row * C + tid + 256 * i] = (bf16)r;
  }
  if (tid == 0) sc[row] = cl * (1.0f / 127.0f);
}

// ---------------- GEMM (m97 structure + split-K EPI4) ----------------
// C[m,n] = sum_k A[m,k]*B[n,k];  A,B internal bf16 (integer-valued).
// EPI 2: out bf16 = relu(sA[m]*cw*val)^2   (w1 -> F; direct, no split)
// EPI 4: atomicAdd raw f32 partial into out (split-K; exact — integer dots < 2^24)
template <int EPI>
__global__ __launch_bounds__(256) void k_gemm(const bf16* __restrict__ A, const bf16* __restrict__ B,
                                              const float* __restrict__ sA,
                                              const float* __restrict__ wsum, float winv,
                                              void* __restrict__ out,
                                              int M, int N, int K, int Kc,
                                              const int* __restrict__ flag) {
  __shared__ __align__(16) bf16 As[128 * 32];
  __shared__ __align__(16) bf16 Bs[128 * 32];
  const int tid = threadIdx.x;
  const int lane = tid & 63;
  const int ml = lane & 15;
  const int q4 = lane >> 4;
  const int wid = tid >> 6;
  const int wM = wid >> 1;
  const int wN = wid & 1;
  const int m0 = blockIdx.y * 128;
  const int n0 = blockIdx.x * 128;

  const int r0 = tid >> 2;          // 0..63
  const int c0 = (tid & 3) * 8;     // 0,8,16,24
  const bf16* Ag0 = A + (size_t)(m0 + r0) * K + c0;
  const bf16* Ag1 = Ag0 + (size_t)64 * K;
  const bf16* Bg0 = B + (size_t)(n0 + r0) * K + c0;
  const bf16* Bg1 = Bg0 + (size_t)64 * K;
  bf16* as0 = &As[wid * 512];
  bf16* as1 = &As[2048 + wid * 512];
  bf16* bs0 = &Bs[wid * 512];
  bf16* bs1 = &Bs[2048 + wid * 512];

  v4f acc[4][4] = {};

  const int kbeg = blockIdx.z * Kc;
  const int kfin = kbeg + Kc;
  for (int k0 = kbeg; k0 < kfin; k0 += 32) {
    __syncthreads();  // prior iteration's readers done before overwrite
    glds16(Ag0 + k0, as0);
    glds16(Ag1 + k0, as1);
    glds16(Bg0 + k0, bs0);
    glds16(Bg1 + k0, bs1);
    __syncthreads();  // staging complete (barrier drains vmcnt)
    v8bf af[4], bfr[4];
#pragma unroll
    for (int i = 0; i < 4; i++) af[i] = *(const v8bf*)&As[(wM * 64 + i * 16 + ml) * 32 + q4 * 8];
#pragma unroll
    for (int j = 0; j < 4; j++) bfr[j] = *(const v8bf*)&Bs[(wN * 64 + j * 16 + ml) * 32 + q4 * 8];
#pragma unroll
    for (int i = 0; i < 4; i++)
#pragma unroll
      for (int j = 0; j < 4; j++) acc[i][j] = MFMA_BF16(af[i], bfr[j], acc[i][j]);
  }

  if (EPI == 4) {
    float* ob = (float*)out;
#pragma unroll
    for (int i = 0; i < 4; i++)
#pragma unroll
      for (int r = 0; r < 4; r++) {
        const int row = m0 + wM * 64 + i * 16 + q4 * 4 + r;
#pragma unroll
        for (int j = 0; j < 4; j++) {
          const int col = n0 + wN * 64 + j * 16 + ml;
          atomicAdd(ob + (size_t)row * N + col, acc[i][j][r]);
        }
      }
    return;
  }

  // EPI == 2 (direct relu^2 bf16)
  const float cw = fmaxf(wsum[0] * winv, 1e-5f);
#pragma unroll
  for (int i = 0; i < 4; i++) {
#pragma unroll
    for (int r = 0; r < 4; r++) {
      const int row = m0 + wM * 64 + i * 16 + q4 * 4 + r;
      const float sa = sA[row] * cw;
#pragma unroll
      for (int j = 0; j < 4; j++) {
        const int col = n0 + wN * 64 + j * 16 + ml;
        const float val = acc[i][j][r] * sa;
        float u = fmaxf(val, 0.0f);
        ((bf16*)out)[(size_t)row * N + col] = (bf16)(u * u);
      }
    }
  }
}

// ---------------- split-K scale/residual epilogues ----------------
// MODE 0: out bf16 = acc*sA[row]*cw                     (Q, K)
// MODE 1: out f32  = resid(flag-typed) + acc*sA[row]*cw (x1)
// MODE 2: out flag-typed = x1(f32) + acc*sA[row]*cw     (final)
// MODE 3: out bf16 = acc*sA[col]*cw                     (Vt: row=d, col-scale s1[t])
template <int MODE>
__global__ __launch_bounds__(256) void k_epi(const float* __restrict__ acc, int lda, int cofs,
                                             int ncols,
                                             const float* __restrict__ sA,
                                             const float* __restrict__ wsum, float winv,
                                             const void* __restrict__ resid,
                                             void* __restrict__ out,
                                             const int* __restrict__ flag) {
  const int row = blockIdx.x, tid = threadIdx.x;
  const float cw = fmaxf(wsum[0] * winv, 1e-5f);
  const float srow = (MODE == 3) ? cw : sA[row] * cw;
  const int f32 = flag[0];
  for (int c = tid * 4; c < ncols; c += 1024) {
    float4 a = *(const float4*)(acc + (size_t)row * lda + cofs + c);
    float s0 = srow, s1 = srow, s2 = srow, s3 = srow;
    if (MODE == 3) {
      float4 sc = *(const float4*)(sA + c);
      s0 *= sc.x; s1 *= sc.y; s2 *= sc.z; s3 *= sc.w;
    }
    const float v0 = a.x * s0, v1 = a.y * s1, v2 = a.z * s2, v3 = a.w * s3;
    const size_t o = (size_t)row * ncols + c;
    if (MODE == 0 || MODE == 3) {
      v4bf r;
      r[0] = (bf16)v0; r[1] = (bf16)v1; r[2] = (bf16)v2; r[3] = (bf16)v3;
      *(v4bf*)((bf16*)out + o) = r;
    } else if (MODE == 1) {
      float4 rv;
      if (f32) {
        rv = *(const float4*)((const float*)resid + o);
      } else {
        const v4bf rb = *(const v4bf*)((const bf16*)resid + o);
        rv = make_float4((float)rb[0], (float)rb[1], (float)rb[2], (float)rb[3]);
      }
      *(float4*)((float*)out + o) = make_float4(rv.x + v0, rv.y + v1, rv.z + v2, rv.w + v3);
    } else {  // MODE 2
      const float4 rv = *(const float4*)((const float*)resid + o);
      const float o0 = rv.x + v0, o1 = rv.y + v1, o2 = rv.z + v2, o3 = rv.w + v3;
      if (f32) {
        *(float4*)((float*)out + o) = make_float4(o0, o1, o2, o3);
      } else {
        v4bf r;
        r[0] = (bf16)o0; r[1] = (bf16)o1; r[2] = (bf16)o2; r[3] = (bf16)o3;
        *(v4bf*)((bf16*)out + o) = r;
      }
    }
  }
}

// ---------------- MFMA flash attention (causal, GQA 32q/8kv heads, D=64) ----------------
// Swapped-operand 32x32 structure; softmax fully in-register; no LDS, no barriers.
__global__ __launch_bounds__(64) void k_attn(const bf16* __restrict__ Q, const bf16* __restrict__ Kb,
                                             const bf16* __restrict__ Vt, bf16* __restrict__ O) {
  const int h = blockIdx.y;
  const int kvh = h >> 2;
  const int t = (blockIdx.x + ((h >> 2) << 3)) & 63;  // balanced q-tile swizzle
  const int qw0 = t * 32;
  const int lane = threadIdx.x;
  const int ql = lane & 31;
  const int hi = lane >> 5;

  v8bf qf[4];
  {
    const bf16* qp = Q + (size_t)(qw0 + ql) * 2048 + h * 64 + hi * 8;
#pragma unroll
    for (int c = 0; c < 4; c++) qf[c] = *(const v8bf*)(qp + c * 16);
  }

  float m = -1e30f, l = 0.0f;
  f32x16 acc0 = {}, acc1 = {};

  const bf16* kbase = Kb + kvh * 64 + hi * 8;
  const bf16* vbase = Vt + (size_t)(kvh * 64 + ql) * 2048 + hi * 8;

  for (int kb = 0; kb <= qw0; kb += 32) {
    f32x16 s = {};
    {
      const bf16* kp = kbase + (size_t)(kb + ql) * 512;
#pragma unroll
      for (int c = 0; c < 4; c++) {
        const v8bf kf = *(const v8bf*)(kp + c * 16);
        s = MFMA32(kf, qf[c], s);
      }
    }
    const bool diag = (kb == qw0);
    float p[16];
    float rm = -1e30f;
#pragma unroll
    for (int r = 0; r < 16; r++) {
      float v = s[r] * 0.125f;
      const int koff = (r & 3) + ((r >> 2) << 3) + (hi << 2);
      if (diag && koff > ql) v = -1e30f;
      p[r] = v;
      rm = fmaxf(rm, v);
    }
    rm = fmaxf(rm, __shfl_xor(rm, 32));
    const float mn = fmaxf(m, rm);
    const float alpha = __expf(m - mn);
    m = mn;
    float rs = 0.0f;
#pragma unroll
    for (int r = 0; r < 16; r++) {
      p[r] = __expf(p[r] - mn);
      rs += p[r];
    }
    rs += __shfl_xor(rs, 32);
    l = l * alpha + rs;
#pragma unroll
    for (int r = 0; r < 16; r++) { acc0[r] *= alpha; acc1[r] *= alpha; }

    unsigned int w0 = packbf(p[0], p[1]),   w2 = packbf(p[4], p[5]);
    unsigned int w1 = packbf(p[2], p[3]),   w3 = packbf(p[6], p[7]);
    unsigned int x0 = packbf(p[8], p[9]),   x2 = packbf(p[12], p[13]);
    unsigned int x1 = packbf(p[10], p[11]), x3 = packbf(p[14], p[15]);
    asm("v_permlane32_swap_b32 %0, %1" : "+v"(w0), "+v"(w2));
    asm("v_permlane32_swap_b32 %0, %1" : "+v"(w1), "+v"(w3));
    asm("v_permlane32_swap_b32 %0, %1" : "+v"(x0), "+v"(x2));
    asm("v_permlane32_swap_b32 %0, %1" : "+v"(x1), "+v"(x3));
    union BU { unsigned int u[4]; v8bf v; } B0, B1;
    B0.u[0] = w0; B0.u[1] = w1; B0.u[2] = w2; B0.u[3] = w3;
    B1.u[0] = x0; B1.u[1] = x1; B1.u[2] = x2; B1.u[3] = x3;

    const bf16* vp = vbase + kb;
    const v8bf v00 = *(const v8bf*)(vp);
    const v8bf v01 = *(const v8bf*)(vp + 16);
    const v8bf v10 = *(const v8bf*)(vp + (size_t)32 * 2048);
    const v8bf v11 = *(const v8bf*)(vp + (size_t)32 * 2048 + 16);
    acc0 = MFMA32(v00, B0.v, acc0);
    acc0 = MFMA32(v01, B1.v, acc0);
    acc1 = MFMA32(v10, B0.v, acc1);
    acc1 = MFMA32(v11, B1.v, acc1);
  }

  const float inv = 1.0f / l;
  unsigned int* op = (unsigned int*)(O + (size_t)(qw0 + ql) * 2048 + h * 64);
#pragma unroll
  for (int r = 0; r < 16; r += 2) {
    const int d = (r & 3) + ((r >> 2) << 3) + (hi << 2);
    op[d >> 1] = packbf(acc0[r] * inv, acc0[r + 1] * inv);
    op[(d >> 1) + 16] = packbf(acc1[r] * inv, acc1[r + 1] * inv);
  }
}

// ---------------- launcher ----------------
// Workspace (96 MB + 64 KB), offsets from `big`:
//   0-32   w1z  -> (after gemm<2>) w2z
//   32-40  wqz  -> Ob (attn out) -> [32-48) accO -> [32-64) Fb/fq
//   40-42  wkz       42-44 wvz
//   44-46  Vt        46-48 Kbuf
//   48-56  woz
//   56-64  Qb
//   64-84  accQK (f32 [2048][2560]) -> 64-80 x1 (f32)
//   84-88  accVt (f32 [512][2048])
//   80-96  accF (f32, after xq2 dead; 80-84 was accQK tail, 84-88 accVt)
//   88-96  xq1 / oq / xq2
extern "C" void kernel_launch(void* const* d_in, const int* in_sizes, int n_in, void* d_out,
                              int out_size, void* d_ws, size_t ws_size, hipStream_t stream) {
  const void* x = d_in[0];
  const void* g1 = d_in[1];
  const void* b1 = d_in[2];
  const void* g2 = d_in[3];
  const void* b2 = d_in[4];
  const void* wq = d_in[5];
  const void* wk = d_in[6];
  const void* wv = d_in[7];
  const void* wo = d_in[8];
  const void* w1 = d_in[9];
  const void* w2 = d_in[10];

  char* ws = (char*)d_ws;
  const size_t MB = 1ull << 20;
  float* wsum = (float*)ws;
  float* s1 = (float*)(ws + 8192);
  float* so = (float*)(ws + 16384);
  float* s2 = (float*)(ws + 24576);
  float* sf = (float*)(ws + 32768);
  int* flag = (int*)(ws + 40960);
  char* big = ws + 65536;

  bf16* w1z = (bf16*)(big);
  bf16* w2z = (bf16*)(big);
  bf16* wqz = (bf16*)(big + 32 * MB);   // [2560][2048] contiguous with wkz
  bf16* wkz = (bf16*)(big + 40 * MB);
  bf16* wvz = (bf16*)(big + 42 * MB);
  bf16* Vt  = (bf16*)(big + 44 * MB);
  bf16* Kbuf= (bf16*)(big + 46 * MB);
  bf16* woz = (bf16*)(big + 48 * MB);
  bf16* Qb  = (bf16*)(big + 56 * MB);
  float* accQK = (float*)(big + 64 * MB);  // [2048][2560]
  float* accVt = (float*)(big + 84 * MB);  // [512][2048]
  float* x1    = (float*)(big + 64 * MB);  // after accQK dead
  float* accO  = (float*)(big + 32 * MB);  // [2048][2048], after Ob consumed
  float* accF  = (float*)(big + 80 * MB);  // [2048][2048], after xq2 dead
  bf16* Ob  = (bf16*)(big + 32 * MB);
  bf16* Fb  = (bf16*)(big + 32 * MB);
  bf16* fq  = Fb;
  bf16* xq1 = (bf16*)(big + 88 * MB);
  bf16* oq  = xq1;
  bf16* xq2 = xq1;

  const float invD2 = 1.0f / 4194304.0f;
  const float invKV = 1.0f / 1048576.0f;
  const float invF = 1.0f / 16777216.0f;

  k_sniff<<<1, 64, 0, stream>>>((const unsigned short*)x, flag);
  k_zero<<<1, 64, 0, stream>>>(wsum, 8);
  // zero accQK+accVt (contiguous 24MB @64-88)
  k_zerof<<<6144, 256, 0, stream>>>((float4*)accQK);

  k_abssum<<<512, 256, 0, stream>>>(wq, 2048 * 2048, flag, wsum + 0);
  k_abssum<<<512, 256, 0, stream>>>(wk, 512 * 2048, flag, wsum + 1);
  k_abssum<<<512, 256, 0, stream>>>(wv, 512 * 2048, flag, wsum + 2);
  k_abssum<<<512, 256, 0, stream>>>(wo, 2048 * 2048, flag, wsum + 3);
  k_abssum<<<512, 256, 0, stream>>>(w1, 8192 * 2048, flag, wsum + 4);
  k_abssum<<<512, 256, 0, stream>>>(w2, 2048 * 8192, flag, wsum + 5);
  k_wquant<<<2048, 256, 0, stream>>>(wq, wqz, wsum + 0, invD2, flag);
  k_wquant<<<512, 256, 0, stream>>>(wk, wkz, wsum + 1, invKV, flag);
  k_wquant<<<512, 256, 0, stream>>>(wv, wvz, wsum + 2, invKV, flag);
  k_wquant<<<2048, 256, 0, stream>>>(wo, woz, wsum + 3, invD2, flag);
  k_wquant<<<8192, 256, 0, stream>>>(w1, w1z, wsum + 4, invF, flag);

  // ---- attention sublayer ----
  k_lnq<false><<<2048, 256, 0, stream>>>(x, g1, b1, xq1, s1, flag);
  // fused Q+K projection: B = [wqz;wkz] (2560 rows), split-K x4 -> accQK
  k_gemm<4><<<dim3(20, 16, 4), 256, 0, stream>>>(xq1, wqz, s1, wsum + 0, invD2, accQK,
                                                 2048, 2560, 2048, 512, flag);
  // V^T directly: C[d][t] = wvz[d].xq1[t], split-K x4 -> accVt
  k_gemm<4><<<dim3(16, 4, 4), 256, 0, stream>>>(wvz, xq1, s1, wsum + 2, invKV, accVt,
                                                512, 2048, 2048, 512, flag);
  k_epi<0><<<2048, 256, 0, stream>>>(accQK, 2560, 0, 2048, s1, wsum + 0, invD2, nullptr, Qb, flag);
  k_epi<0><<<2048, 256, 0, stream>>>(accQK, 2560, 2048, 512, s1, wsum + 1, invKV, nullptr, Kbuf, flag);
  k_epi<3><<<512, 256, 0, stream>>>(accVt, 2048, 0, 2048, s1, wsum + 2, invKV, nullptr, Vt, flag);
  k_attn<<<dim3(64, 32), 64, 0, stream>>>(Qb, Kbuf, Vt, Ob);
  k_rowq<8><<<2048, 256, 0, stream>>>(Ob, oq, so);
  k_zerof<<<4096, 256, 0, stream>>>((float4*)accO);  // after rowq read Ob
  k_gemm<4><<<dim3(16, 16, 4), 256, 0, stream>>>(oq, woz, so, wsum + 3, invD2, accO,
                                                 2048, 2048, 2048, 512, flag);
  k_epi<1><<<2048, 256, 0, stream>>>(accO, 2048, 0, 2048, so, wsum + 3, invD2, x, x1, flag);

  // ---- FFN sublayer ----
  k_lnq<true><<<2048, 256, 0, stream>>>(x1, g2, b2, xq2, s2, flag);
  k_gemm<2><<<dim3(64, 16, 1), 256, 0, stream>>>(xq2, w1z, s2, wsum + 4, invF, Fb,
                                                 2048, 8192, 2048, 2048, flag);
  k_wquant<<<8192, 256, 0, stream>>>(w2, w2z, wsum + 5, invF, flag);
  k_rowq<32><<<2048, 256, 0, stream>>>(Fb, fq, sf);
  k_zerof<<<4096, 256, 0, stream>>>((float4*)accF);  // after gemm<2>/rowq (xq2, Ob dead)
  k_gemm<4><<<dim3(16, 16, 4), 256, 0, stream>>>(fq, w2z, sf, wsum + 5, invF, accF,
                                                 2048, 2048, 8192, 2048, flag);
  k_epi<2><<<2048, 256, 0, stream>>>(accF, 2048, 0, 2048, sf, wsum + 5, invF, x1, d_out, flag);
}

// Round 3
// 715.793 us; speedup vs baseline: 1.4337x; 1.1839x over previous
//
#include <hip/hip_runtime.h>
#include <hip/hip_bf16.h>
#include <stdint.h>

typedef __bf16 bf16;
typedef signed char i8;
typedef __bf16 v8bf __attribute__((ext_vector_type(8)));
typedef __bf16 v4bf __attribute__((ext_vector_type(4)));
typedef signed char v8i8 __attribute__((ext_vector_type(8)));
typedef int    v4i  __attribute__((ext_vector_type(4)));
typedef float  f32x16 __attribute__((ext_vector_type(16)));

#define MFMA32(a,b,c)   __builtin_amdgcn_mfma_f32_32x32x16_bf16((a),(b),(c),0,0,0)
#define MFMA_I8(a,b,c)  __builtin_amdgcn_mfma_i32_16x16x64_i8((a),(b),(c),0,0,0)

__device__ __forceinline__ void glds16(const void* g, void* l) {
  __builtin_amdgcn_global_load_lds(
      (const __attribute__((address_space(1))) void*)g,
      (__attribute__((address_space(3))) void*)l, 16, 0, 0);
}

__device__ __forceinline__ float wred_sum(float v) {
#pragma unroll
  for (int o = 32; o; o >>= 1) v += __shfl_xor(v, o);
  return v;
}
__device__ __forceinline__ float wred_max(float v) {
#pragma unroll
  for (int o = 32; o; o >>= 1) v = fmaxf(v, __shfl_xor(v, o));
  return v;
}

__device__ __forceinline__ unsigned int packbf(float a, float b) {
  union { bf16 h[2]; unsigned int u; } x;
  x.h[0] = (bf16)a; x.h[1] = (bf16)b;
  return x.u;
}

// ---------------- dtype sniffer (inputs turned out fp32; keep robust) ----------------
__global__ void k_sniff(const unsigned short* __restrict__ x, int* __restrict__ flag) {
  int cnt = 0;
  for (int i = threadIdx.x; i < 2048; i += 64) {
    const unsigned short u = x[i];
    const int e = (u >> 7) & 0xFF;
    if (u == 0 || (e >= 100 && e <= 140)) cnt++;
  }
#pragma unroll
  for (int o = 32; o; o >>= 1) cnt += __shfl_xor(cnt, o);
  if (threadIdx.x == 0) flag[0] = (cnt >= 1844) ? 0 : 1;  // 0 = bf16, 1 = f32
}

// ---------------- small utility kernels ----------------

__global__ void k_zero(float* p, int n) {
  int i = threadIdx.x;
  if (i < n) p[i] = 0.0f;
}

// zero a float4-aligned buffer; grid = bytes/16/256
__global__ __launch_bounds__(256) void k_zerof(float4* __restrict__ p) {
  p[(size_t)blockIdx.x * 256 + threadIdx.x] = make_float4(0.f, 0.f, 0.f, 0.f);
}

__global__ __launch_bounds__(256) void k_abssum(const void* __restrict__ w, int n,
                                                const int* __restrict__ flag,
                                                float* __restrict__ out) {
  const int tid = threadIdx.x;
  const int f32 = flag[0];
  __shared__ float sred[4];
  float s = 0.0f;
  if (f32) {
    const float4* p = (const float4*)w;
    for (int i = (blockIdx.x * 256 + tid) * 2; i * 4 < n; i += gridDim.x * 512) {
      float4 a = p[i], b = p[i + 1];
      s += fabsf(a.x) + fabsf(a.y) + fabsf(a.z) + fabsf(a.w) +
           fabsf(b.x) + fabsf(b.y) + fabsf(b.z) + fabsf(b.w);
    }
  } else {
    const bf16* p = (const bf16*)w;
    for (int i = (blockIdx.x * 256 + tid) * 8; i < n; i += gridDim.x * 2048) {
      v8bf v = *(const v8bf*)(p + i);
#pragma unroll
      for (int j = 0; j < 8; j++) s += fabsf((float)v[j]);
    }
  }
  s = wred_sum(s);
  if ((tid & 63) == 0) sred[tid >> 6] = s;
  __syncthreads();
  if (tid == 0) atomicAdd(out, sred[0] + sred[1] + sred[2] + sred[3]);
}

// ternary weight quant -> int8
__global__ __launch_bounds__(256) void k_wquant(const void* __restrict__ w, i8* __restrict__ o,
                                                const float* __restrict__ sum, float invn,
                                                const int* __restrict__ flag) {
  const int gid = blockIdx.x * 256 + threadIdx.x;
  const int i = gid * 8;
  const float ws = 1.0f / fmaxf(sum[0] * invn, 1e-5f);
  const int f32 = flag[0];
  float v[8];
  if (f32) {
    float4 a = ((const float4*)w)[gid * 2];
    float4 b = ((const float4*)w)[gid * 2 + 1];
    v[0] = a.x; v[1] = a.y; v[2] = a.z; v[3] = a.w;
    v[4] = b.x; v[5] = b.y; v[6] = b.z; v[7] = b.w;
  } else {
    v8bf t = *(const v8bf*)((const bf16*)w + i);
#pragma unroll
    for (int j = 0; j < 8; j++) v[j] = (float)t[j];
  }
  v8i8 r;
#pragma unroll
  for (int j = 0; j < 8; j++) {
    float t = rintf(v[j] * ws);
    r[j] = (i8)fminf(fmaxf(t, -1.0f), 1.0f);
  }
  *(v8i8*)(o + i) = r;
}

// LayerNorm + per-row absmax quantize -> int8.
template <bool XINT>
__global__ __launch_bounds__(256) void k_lnq(const void* __restrict__ x, const void* __restrict__ g,
                                             const void* __restrict__ b, i8* __restrict__ q,
                                             float* __restrict__ sc, const int* __restrict__ flag) {
  const int row = blockIdx.x, tid = threadIdx.x;
  const int f32 = flag[0];
  __shared__ float sred[4];
  float v[8];
#pragma unroll
  for (int i = 0; i < 8; i++) {
    const size_t idx = (size_t)row * 2048 + tid + 256 * i;
    if (XINT)      v[i] = ((const float*)x)[idx];
    else if (f32)  v[i] = ((const float*)x)[idx];
    else           v[i] = (float)((const bf16*)x)[idx];
  }
  float s = 0.0f;
#pragma unroll
  for (int i = 0; i < 8; i++) s += v[i];
  s = wred_sum(s);
  if ((tid & 63) == 0) sred[tid >> 6] = s;
  __syncthreads();
  const float mean = (sred[0] + sred[1] + sred[2] + sred[3]) * (1.0f / 2048.0f);
  __syncthreads();
  float vs = 0.0f;
#pragma unroll
  for (int i = 0; i < 8; i++) { float d = v[i] - mean; vs += d * d; }
  vs = wred_sum(vs);
  if ((tid & 63) == 0) sred[tid >> 6] = vs;
  __syncthreads();
  const float rstd = rsqrtf((sred[0] + sred[1] + sred[2] + sred[3]) * (1.0f / 2048.0f) + 1e-6f);
  __syncthreads();
  float hq[8];
  float am = 0.0f;
#pragma unroll
  for (int i = 0; i < 8; i++) {
    const int c = tid + 256 * i;
    const float gv = f32 ? ((const float*)g)[c] : (float)((const bf16*)g)[c];
    const float bv = f32 ? ((const float*)b)[c] : (float)((const bf16*)b)[c];
    hq[i] = (v[i] - mean) * rstd * gv + bv;
    am = fmaxf(am, fabsf(hq[i]));
  }
  am = wred_max(am);
  if ((tid & 63) == 0) sred[tid >> 6] = am;
  __syncthreads();
  am = fmaxf(fmaxf(sred[0], sred[1]), fmaxf(sred[2], sred[3]));
  const float cl = fmaxf(am, 1e-5f);
  const float s127 = 127.0f / cl;
#pragma unroll
  for (int i = 0; i < 8; i++) {
    float r = rintf(hq[i] * s127);
    r = fminf(fmaxf(r, -128.0f), 127.0f);
    q[(size_t)row * 2048 + tid + 256 * i] = (i8)r;
  }
  if (tid == 0) sc[row] = cl * (1.0f / 127.0f);
}

// plain per-row absmax quantize bf16 -> int8
template <int IT>
__global__ __launch_bounds__(256) void k_rowq(const bf16* __restrict__ in, i8* __restrict__ q,
                                              float* __restrict__ sc) {
  const int row = blockIdx.x, tid = threadIdx.x;
  const int C = IT * 256;
  __shared__ float sred[4];
  const bf16* xr = in + (size_t)row * C;
  float v[IT];
  float am = 0.0f;
#pragma unroll
  for (int i = 0; i < IT; i++) {
    v[i] = (float)xr[tid + 256 * i];
    am = fmaxf(am, fabsf(v[i]));
  }
  am = wred_max(am);
  if ((tid & 63) == 0) sred[tid >> 6] = am;
  __syncthreads();
  am = fmaxf(fmaxf(sred[0], sred[1]), fmaxf(sred[2], sred[3]));
  const float cl = fmaxf(am, 1e-5f);
  const float s127 = 127.0f / cl;
#pragma unroll
  for (int i = 0; i < IT; i++) {
    float r = rintf(v[i] * s127);
    r = fminf(fmaxf(r, -128.0f), 127.0f);
    q[(size_t)row * C + tid + 256 * i] = (i8)r;
  }
  if (tid == 0) sc[row] = cl * (1.0f / 127.0f);
}

// ---------------- int8 GEMM (m97 structure, K-step 64, i32 accumulate — exact) ----------------
// C[m,n] = sum_k A[m,k]*B[n,k];  A int8 in [-128,127], B ternary int8.
// EPI 2: out bf16 = relu(sA[m]*cw*val)^2   (w1 -> F; direct, no split)
// EPI 4: atomicAdd i32 partial into out    (split-K; exact integer)
template <int EPI>
__global__ __launch_bounds__(256) void k_gemm(const i8* __restrict__ A, const i8* __restrict__ B,
                                              const float* __restrict__ sA,
                                              const float* __restrict__ wsum, float winv,
                                              void* __restrict__ out,
                                              int M, int N, int K, int Kc,
                                              const int* __restrict__ flag) {
  __shared__ __align__(16) i8 As[128 * 64];
  __shared__ __align__(16) i8 Bs[128 * 64];
  const int tid = threadIdx.x;
  const int lane = tid & 63;
  const int ml = lane & 15;
  const int q4 = lane >> 4;
  const int wid = tid >> 6;
  const int wM = wid >> 1;
  const int wN = wid & 1;
  const int m0 = blockIdx.y * 128;
  const int n0 = blockIdx.x * 128;

  const int r0 = tid >> 2;           // 0..63
  const int c0 = (tid & 3) * 16;     // 0,16,32,48
  const i8* Ag0 = A + (size_t)(m0 + r0) * K + c0;
  const i8* Ag1 = Ag0 + (size_t)64 * K;
  const i8* Bg0 = B + (size_t)(n0 + r0) * K + c0;
  const i8* Bg1 = Bg0 + (size_t)64 * K;
  // lane l of wave w writes LDS at wavebase + l*16B == &As[tid*16]
  i8* as0 = &As[wid * 1024];
  i8* as1 = &As[4096 + wid * 1024];
  i8* bs0 = &Bs[wid * 1024];
  i8* bs1 = &Bs[4096 + wid * 1024];

  v4i acc[4][4] = {};

  const int kbeg = blockIdx.z * Kc;
  const int kfin = kbeg + Kc;
  for (int k0 = kbeg; k0 < kfin; k0 += 64) {
    __syncthreads();  // prior iteration's readers done before overwrite
    glds16(Ag0 + k0, as0);
    glds16(Ag1 + k0, as1);
    glds16(Bg0 + k0, bs0);
    glds16(Bg1 + k0, bs1);
    __syncthreads();  // staging complete (barrier drains vmcnt)
    v4i af[4], bfr[4];
#pragma unroll
    for (int i = 0; i < 4; i++) af[i] = *(const v4i*)&As[(wM * 64 + i * 16 + ml) * 64 + q4 * 16];
#pragma unroll
    for (int j = 0; j < 4; j++) bfr[j] = *(const v4i*)&Bs[(wN * 64 + j * 16 + ml) * 64 + q4 * 16];
#pragma unroll
    for (int i = 0; i < 4; i++)
#pragma unroll
      for (int j = 0; j < 4; j++) acc[i][j] = MFMA_I8(af[i], bfr[j], acc[i][j]);
  }

  if (EPI == 4) {
    int* ob = (int*)out;
#pragma unroll
    for (int i = 0; i < 4; i++)
#pragma unroll
      for (int r = 0; r < 4; r++) {
        const int row = m0 + wM * 64 + i * 16 + q4 * 4 + r;
#pragma unroll
        for (int j = 0; j < 4; j++) {
          const int col = n0 + wN * 64 + j * 16 + ml;
          atomicAdd(ob + (size_t)row * N + col, acc[i][j][r]);
        }
      }
    return;
  }

  // EPI == 2 (direct relu^2 bf16)
  const float cw = fmaxf(wsum[0] * winv, 1e-5f);
#pragma unroll
  for (int i = 0; i < 4; i++) {
#pragma unroll
    for (int r = 0; r < 4; r++) {
      const int row = m0 + wM * 64 + i * 16 + q4 * 4 + r;
      const float sa = sA[row] * cw;
#pragma unroll
      for (int j = 0; j < 4; j++) {
        const int col = n0 + wN * 64 + j * 16 + ml;
        const float val = (float)acc[i][j][r] * sa;
        float u = fmaxf(val, 0.0f);
        ((bf16*)out)[(size_t)row * N + col] = (bf16)(u * u);
      }
    }
  }
}

// ---------------- split-K scale/residual epilogues (i32 acc in) ----------------
// MODE 0: out bf16 = acc*sA[row]*cw                     (Q, K)
// MODE 1: out f32  = resid(flag-typed) + acc*sA[row]*cw (x1)
// MODE 2: out flag-typed = x1(f32) + acc*sA[row]*cw     (final)
// MODE 3: out bf16 = acc*sA[col]*cw                     (Vt: row=d, col-scale s1[t])
template <int MODE>
__global__ __launch_bounds__(256) void k_epi(const int* __restrict__ acc, int lda, int cofs,
                                             int ncols,
                                             const float* __restrict__ sA,
                                             const float* __restrict__ wsum, float winv,
                                             const void* __restrict__ resid,
                                             void* __restrict__ out,
                                             const int* __restrict__ flag) {
  const int row = blockIdx.x, tid = threadIdx.x;
  const float cw = fmaxf(wsum[0] * winv, 1e-5f);
  const float srow = (MODE == 3) ? cw : sA[row] * cw;
  const int f32 = flag[0];
  for (int c = tid * 4; c < ncols; c += 1024) {
    const v4i a = *(const v4i*)(acc + (size_t)row * lda + cofs + c);
    float s0 = srow, s1 = srow, s2 = srow, s3 = srow;
    if (MODE == 3) {
      float4 sc = *(const float4*)(sA + c);
      s0 *= sc.x; s1 *= sc.y; s2 *= sc.z; s3 *= sc.w;
    }
    const float v0 = (float)a[0] * s0, v1 = (float)a[1] * s1;
    const float v2 = (float)a[2] * s2, v3 = (float)a[3] * s3;
    const size_t o = (size_t)row * ncols + c;
    if (MODE == 0 || MODE == 3) {
      v4bf r;
      r[0] = (bf16)v0; r[1] = (bf16)v1; r[2] = (bf16)v2; r[3] = (bf16)v3;
      *(v4bf*)((bf16*)out + o) = r;
    } else if (MODE == 1) {
      float4 rv;
      if (f32) {
        rv = *(const float4*)((const float*)resid + o);
      } else {
        const v4bf rb = *(const v4bf*)((const bf16*)resid + o);
        rv = make_float4((float)rb[0], (float)rb[1], (float)rb[2], (float)rb[3]);
      }
      *(float4*)((float*)out + o) = make_float4(rv.x + v0, rv.y + v1, rv.z + v2, rv.w + v3);
    } else {  // MODE 2
      const float4 rv = *(const float4*)((const float*)resid + o);
      const float o0 = rv.x + v0, o1 = rv.y + v1, o2 = rv.z + v2, o3 = rv.w + v3;
      if (f32) {
        *(float4*)((float*)out + o) = make_float4(o0, o1, o2, o3);
      } else {
        v4bf r;
        r[0] = (bf16)o0; r[1] = (bf16)o1; r[2] = (bf16)o2; r[3] = (bf16)o3;
        *(v4bf*)((bf16*)out + o) = r;
      }
    }
  }
}

// ---------------- MFMA flash attention (causal, GQA 32q/8kv heads, D=64) ----------------
// Swapped-operand 32x32 structure; softmax fully in-register; no LDS, no barriers.
__global__ __launch_bounds__(64) void k_attn(const bf16* __restrict__ Q, const bf16* __restrict__ Kb,
                                             const bf16* __restrict__ Vt, bf16* __restrict__ O) {
  const int h = blockIdx.y;
  const int kvh = h >> 2;
  const int t = (blockIdx.x + ((h >> 2) << 3)) & 63;  // balanced q-tile swizzle
  const int qw0 = t * 32;
  const int lane = threadIdx.x;
  const int ql = lane & 31;
  const int hi = lane >> 5;

  v8bf qf[4];
  {
    const bf16* qp = Q + (size_t)(qw0 + ql) * 2048 + h * 64 + hi * 8;
#pragma unroll
    for (int c = 0; c < 4; c++) qf[c] = *(const v8bf*)(qp + c * 16);
  }

  float m = -1e30f, l = 0.0f;
  f32x16 acc0 = {}, acc1 = {};

  const bf16* kbase = Kb + kvh * 64 + hi * 8;
  const bf16* vbase = Vt + (size_t)(kvh * 64 + ql) * 2048 + hi * 8;

  for (int kb = 0; kb <= qw0; kb += 32) {
    f32x16 s = {};
    {
      const bf16* kp = kbase + (size_t)(kb + ql) * 512;
#pragma unroll
      for (int c = 0; c < 4; c++) {
        const v8bf kf = *(const v8bf*)(kp + c * 16);
        s = MFMA32(kf, qf[c], s);
      }
    }
    const bool diag = (kb == qw0);
    float p[16];
    float rm = -1e30f;
#pragma unroll
    for (int r = 0; r < 16; r++) {
      float v = s[r] * 0.125f;
      const int koff = (r & 3) + ((r >> 2) << 3) + (hi << 2);
      if (diag && koff > ql) v = -1e30f;
      p[r] = v;
      rm = fmaxf(rm, v);
    }
    rm = fmaxf(rm, __shfl_xor(rm, 32));
    const float mn = fmaxf(m, rm);
    const float alpha = __expf(m - mn);
    m = mn;
    float rs = 0.0f;
#pragma unroll
    for (int r = 0; r < 16; r++) {
      p[r] = __expf(p[r] - mn);
      rs += p[r];
    }
    rs += __shfl_xor(rs, 32);
    l = l * alpha + rs;
#pragma unroll
    for (int r = 0; r < 16; r++) { acc0[r] *= alpha; acc1[r] *= alpha; }

    unsigned int w0 = packbf(p[0], p[1]),   w2 = packbf(p[4], p[5]);
    unsigned int w1 = packbf(p[2], p[3]),   w3 = packbf(p[6], p[7]);
    unsigned int x0 = packbf(p[8], p[9]),   x2 = packbf(p[12], p[13]);
    unsigned int x1 = packbf(p[10], p[11]), x3 = packbf(p[14], p[15]);
    asm("v_permlane32_swap_b32 %0, %1" : "+v"(w0), "+v"(w2));
    asm("v_permlane32_swap_b32 %0, %1" : "+v"(w1), "+v"(w3));
    asm("v_permlane32_swap_b32 %0, %1" : "+v"(x0), "+v"(x2));
    asm("v_permlane32_swap_b32 %0, %1" : "+v"(x1), "+v"(x3));
    union BU { unsigned int u[4]; v8bf v; } B0, B1;
    B0.u[0] = w0; B0.u[1] = w1; B0.u[2] = w2; B0.u[3] = w3;
    B1.u[0] = x0; B1.u[1] = x1; B1.u[2] = x2; B1.u[3] = x3;

    const bf16* vp = vbase + kb;
    const v8bf v00 = *(const v8bf*)(vp);
    const v8bf v01 = *(const v8bf*)(vp + 16);
    const v8bf v10 = *(const v8bf*)(vp + (size_t)32 * 2048);
    const v8bf v11 = *(const v8bf*)(vp + (size_t)32 * 2048 + 16);
    acc0 = MFMA32(v00, B0.v, acc0);
    acc0 = MFMA32(v01, B1.v, acc0);
    acc1 = MFMA32(v10, B0.v, acc1);
    acc1 = MFMA32(v11, B1.v, acc1);
  }

  const float inv = 1.0f / l;
  unsigned int* op = (unsigned int*)(O + (size_t)(qw0 + ql) * 2048 + h * 64);
#pragma unroll
  for (int r = 0; r < 16; r += 2) {
    const int d = (r & 3) + ((r >> 2) << 3) + (hi << 2);
    op[d >> 1] = packbf(acc0[r] * inv, acc0[r + 1] * inv);
    op[(d >> 1) + 16] = packbf(acc1[r] * inv, acc1[r + 1] * inv);
  }
}

// ---------------- launcher ----------------
// Workspace (96 MB + 64 KB), offsets from `big` (MB):
//   0-16   w1z(i8)  -> fq(i8, after gemm<2>)
//   16-32  w2z(i8)
//   32-36  wqz(i8)  36-37 wkz (contiguous [2560][2048] for fused QK)
//   37-38  wvz      38-42 woz
//   42-46  xq1 -> oq -> xq2 (i8)
//   46-66  accQK(i32) -> 46-62 accO(i32) -> 46-78 Fb(bf16) -> 46-62 accF(i32)
//   66-70  accVt(i32)
//   70-78  Qb(bf16)   78-80 Kbuf   80-82 Vt   82-90 Ob
//   78-94  x1(f32)  [born after Kbuf/Vt/Ob die]
extern "C" void kernel_launch(void* const* d_in, const int* in_sizes, int n_in, void* d_out,
                              int out_size, void* d_ws, size_t ws_size, hipStream_t stream) {
  const void* x = d_in[0];
  const void* g1 = d_in[1];
  const void* b1 = d_in[2];
  const void* g2 = d_in[3];
  const void* b2 = d_in[4];
  const void* wq = d_in[5];
  const void* wk = d_in[6];
  const void* wv = d_in[7];
  const void* wo = d_in[8];
  const void* w1 = d_in[9];
  const void* w2 = d_in[10];

  char* ws = (char*)d_ws;
  const size_t MB = 1ull << 20;
  float* wsum = (float*)ws;
  float* s1 = (float*)(ws + 8192);
  float* so = (float*)(ws + 16384);
  float* s2 = (float*)(ws + 24576);
  float* sf = (float*)(ws + 32768);
  int* flag = (int*)(ws + 40960);
  char* big = ws + 65536;

  i8* w1z = (i8*)(big);
  i8* fq  = (i8*)(big);
  i8* w2z = (i8*)(big + 16 * MB);
  i8* wqz = (i8*)(big + 32 * MB);   // [2560][2048] contiguous with wkz
  i8* wkz = (i8*)(big + 36 * MB);
  i8* wvz = (i8*)(big + 37 * MB);
  i8* woz = (i8*)(big + 38 * MB);
  i8* xq1 = (i8*)(big + 42 * MB);
  i8* oq  = xq1;
  i8* xq2 = xq1;
  int* accQK = (int*)(big + 46 * MB);   // [2048][2560]
  int* accO  = (int*)(big + 46 * MB);   // [2048][2048]
  bf16* Fb   = (bf16*)(big + 46 * MB);  // [2048][8192]
  int* accF  = (int*)(big + 46 * MB);   // [2048][2048]
  int* accVt = (int*)(big + 66 * MB);   // [512][2048]
  bf16* Qb   = (bf16*)(big + 70 * MB);
  bf16* Kbuf = (bf16*)(big + 78 * MB);
  bf16* Vt   = (bf16*)(big + 80 * MB);
  bf16* Ob   = (bf16*)(big + 82 * MB);
  float* x1  = (float*)(big + 78 * MB);

  const float invD2 = 1.0f / 4194304.0f;
  const float invKV = 1.0f / 1048576.0f;
  const float invF = 1.0f / 16777216.0f;

  k_sniff<<<1, 64, 0, stream>>>((const unsigned short*)x, flag);
  k_zero<<<1, 64, 0, stream>>>(wsum, 8);
  // zero accQK+accVt (contiguous 24MB @46-70)
  k_zerof<<<6144, 256, 0, stream>>>((float4*)accQK);

  k_abssum<<<512, 256, 0, stream>>>(wq, 2048 * 2048, flag, wsum + 0);
  k_abssum<<<512, 256, 0, stream>>>(wk, 512 * 2048, flag, wsum + 1);
  k_abssum<<<512, 256, 0, stream>>>(wv, 512 * 2048, flag, wsum + 2);
  k_abssum<<<512, 256, 0, stream>>>(wo, 2048 * 2048, flag, wsum + 3);
  k_abssum<<<512, 256, 0, stream>>>(w1, 8192 * 2048, flag, wsum + 4);
  k_abssum<<<512, 256, 0, stream>>>(w2, 2048 * 8192, flag, wsum + 5);
  k_wquant<<<2048, 256, 0, stream>>>(wq, wqz, wsum + 0, invD2, flag);
  k_wquant<<<512, 256, 0, stream>>>(wk, wkz, wsum + 1, invKV, flag);
  k_wquant<<<512, 256, 0, stream>>>(wv, wvz, wsum + 2, invKV, flag);
  k_wquant<<<2048, 256, 0, stream>>>(wo, woz, wsum + 3, invD2, flag);
  k_wquant<<<8192, 256, 0, stream>>>(w1, w1z, wsum + 4, invF, flag);
  k_wquant<<<8192, 256, 0, stream>>>(w2, w2z, wsum + 5, invF, flag);

  // ---- attention sublayer ----
  k_lnq<false><<<2048, 256, 0, stream>>>(x, g1, b1, xq1, s1, flag);
  // fused Q+K projection: B = [wqz;wkz] (2560 rows), split-K x4 -> accQK
  k_gemm<4><<<dim3(20, 16, 4), 256, 0, stream>>>(xq1, wqz, s1, wsum + 0, invD2, accQK,
                                                 2048, 2560, 2048, 512, flag);
  // V^T directly: C[d][t] = wvz[d].xq1[t], split-K x4 -> accVt
  k_gemm<4><<<dim3(16, 4, 4), 256, 0, stream>>>(wvz, xq1, s1, wsum + 2, invKV, accVt,
                                                512, 2048, 2048, 512, flag);
  k_epi<0><<<2048, 256, 0, stream>>>(accQK, 2560, 0, 2048, s1, wsum + 0, invD2, nullptr, Qb, flag);
  k_epi<0><<<2048, 256, 0, stream>>>(accQK, 2560, 2048, 512, s1, wsum + 1, invKV, nullptr, Kbuf, flag);
  k_epi<3><<<512, 256, 0, stream>>>(accVt, 2048, 0, 2048, s1, wsum + 2, invKV, nullptr, Vt, flag);
  k_attn<<<dim3(64, 32), 64, 0, stream>>>(Qb, Kbuf, Vt, Ob);
  k_rowq<8><<<2048, 256, 0, stream>>>(Ob, oq, so);
  k_zerof<<<4096, 256, 0, stream>>>((float4*)accO);  // after epis read accQK
  k_gemm<4><<<dim3(16, 16, 4), 256, 0, stream>>>(oq, woz, so, wsum + 3, invD2, accO,
                                                 2048, 2048, 2048, 512, flag);
  k_epi<1><<<2048, 256, 0, stream>>>(accO, 2048, 0, 2048, so, wsum + 3, invD2, x, x1, flag);

  // ---- FFN sublayer ----
  k_lnq<true><<<2048, 256, 0, stream>>>(x1, g2, b2, xq2, s2, flag);
  k_gemm<2><<<dim3(64, 16, 1), 256, 0, stream>>>(xq2, w1z, s2, wsum + 4, invF, Fb,
                                                 2048, 8192, 2048, 2048, flag);
  k_rowq<32><<<2048, 256, 0, stream>>>(Fb, fq, sf);  // fq overwrites dead w1z
  k_zerof<<<4096, 256, 0, stream>>>((float4*)accF);  // after rowq read Fb
  k_gemm<4><<<dim3(16, 16, 4), 256, 0, stream>>>(fq, w2z, sf, wsum + 5, invF, accF,
                                                 2048, 2048, 8192, 2048, flag);
  k_epi<2><<<2048, 256, 0, stream>>>(accF, 2048, 0, 2048, sf, wsum + 5, invF, x1, d_out, flag);
}